// Round 7
// baseline (291.399 us; speedup 1.0000x reference)
//
#include <hip/hip_runtime.h>
#include <stdint.h>

// EdgeNetwork per-edge MLP — round 14: VALU cut, evidence-backed.
//  r13 post-mortem: pk-asm (V_PK_*_F32 op_sel_hi defaults) was THE bug;
//  fused v_add_f32_dpp is exonerated (r11 vs r12: error unchanged when it
//  was reverted). r13 passed at 164us, VALUBusy 56.5% = 93us of VALU issue
//  (~540 instr/wave-mt) vs HBM 29% / MFMA 12% -> VALU-issue-bound.
//  r14 cuts ~110 VALU/mt:
//   (a) fused v_add_f32_dpp reductions (1 instr/step vs mov_dpp+add):
//       lnstats x2 + final po allreduce, 160 -> 80 instr/mt. s_nop 1 inside
//       each asm block guards the VALU-write->DPP-read hazard; >=4 dep
//       distance within blocks.
//   (b) bias-as-C-input: persistent broadcast frags B1F/B2F feed the first
//       MFMA of each K-chain -> deletes 32 v_mov acc-inits/mt.
//  Partial sums stay plain C++ vector math (NO pk asm).

#define TPB 256
#define NEG_SLOPE 0.1f
#define LN_EPS    1e-5f

typedef __attribute__((ext_vector_type(8))) short short8;   // 8 bf16 (4 VGPR)
typedef __attribute__((ext_vector_type(4))) float f32x4;    // 4 f32

__device__ __forceinline__ uint32_t fb(float x) {
  union { float f; uint32_t u; } c; c.f = x; return c.u;
}
__device__ __forceinline__ float bf(uint32_t x) {
  union { uint32_t u; float f; } c; c.u = x; return c.f;
}
// ---- f32 pair -> packed bf16 (RNE), 1 instr; src0 -> low half ----
__device__ __forceinline__ uint32_t cvtpk(float a, float b) {
  uint32_t r; asm("v_cvt_pk_bf16_f32 %0, %1, %2" : "=v"(r) : "v"(a), "v"(b));
  return r;
}
__device__ __forceinline__ short8 cvt8(f32x4 a, f32x4 b) {
  union { short8 s; uint32_t u[4]; } r;
  r.u[0] = cvtpk(a[0], a[1]);
  r.u[1] = cvtpk(a[2], a[3]);
  r.u[2] = cvtpk(b[0], b[1]);
  r.u[3] = cvtpk(b[2], b[3]);
  return r.s;
}
__device__ __forceinline__ short bf16rne(float x) {   // staging (one-time)
  uint32_t u = fb(x);
  return (short)((u + 0x7fffu + ((u >> 16) & 1u)) >> 16);
}

// Fused DPP allreduce over each row of 16 lanes: v += ror(v, n), n=1,2,4,8.
// s_nop 1 inside the block guards the 2-wait-state VALU-write->DPP-read
// hazard at entry; within/between blocks the dependent reuse distance is
// >= 4 (DPP4) / 8 (DPP8). Exonerated by the r11/r12 bisect.
#define DPP8(ctrl, a0,a1,a2,a3,a4,a5,a6,a7)                                  \
  asm volatile(                                                              \
    "s_nop 1\n\t"                                                            \
    "v_add_f32_dpp %0, %0, %0 " ctrl " row_mask:0xf bank_mask:0xf\n\t"       \
    "v_add_f32_dpp %1, %1, %1 " ctrl " row_mask:0xf bank_mask:0xf\n\t"       \
    "v_add_f32_dpp %2, %2, %2 " ctrl " row_mask:0xf bank_mask:0xf\n\t"       \
    "v_add_f32_dpp %3, %3, %3 " ctrl " row_mask:0xf bank_mask:0xf\n\t"       \
    "v_add_f32_dpp %4, %4, %4 " ctrl " row_mask:0xf bank_mask:0xf\n\t"       \
    "v_add_f32_dpp %5, %5, %5 " ctrl " row_mask:0xf bank_mask:0xf\n\t"       \
    "v_add_f32_dpp %6, %6, %6 " ctrl " row_mask:0xf bank_mask:0xf\n\t"       \
    "v_add_f32_dpp %7, %7, %7 " ctrl " row_mask:0xf bank_mask:0xf"           \
    : "+v"(a0), "+v"(a1), "+v"(a2), "+v"(a3),                                \
      "+v"(a4), "+v"(a5), "+v"(a6), "+v"(a7))

#define DPP4(ctrl, a0,a1,a2,a3)                                              \
  asm volatile(                                                              \
    "s_nop 1\n\t"                                                            \
    "v_add_f32_dpp %0, %0, %0 " ctrl " row_mask:0xf bank_mask:0xf\n\t"       \
    "v_add_f32_dpp %1, %1, %1 " ctrl " row_mask:0xf bank_mask:0xf\n\t"       \
    "v_add_f32_dpp %2, %2, %2 " ctrl " row_mask:0xf bank_mask:0xf\n\t"       \
    "v_add_f32_dpp %3, %3, %3 " ctrl " row_mask:0xf bank_mask:0xf"           \
    : "+v"(a0), "+v"(a1), "+v"(a2), "+v"(a3))

// LN stats over 64 features held as acc[4] (cols ln+16*jt, rows quad*4+r).
// Partial sums: plain C++ vector math. Cross-lane: fused DPP (8 chains).
__device__ __forceinline__ void lnstats(const f32x4& a0, const f32x4& a1,
                                        const f32x4& a2, const f32x4& a3,
                                        f32x4& mu, f32x4& rs) {
  f32x4 sv = a0 + a1 + a2 + a3;
  f32x4 qv = a0 * a0 + a1 * a1 + a2 * a2 + a3 * a3;
  float s0 = sv[0], s1 = sv[1], s2 = sv[2], s3 = sv[3];
  float q0 = qv[0], q1 = qv[1], q2 = qv[2], q3 = qv[3];
  DPP8("row_ror:1", s0, s1, s2, s3, q0, q1, q2, q3);
  DPP8("row_ror:2", s0, s1, s2, s3, q0, q1, q2, q3);
  DPP8("row_ror:4", s0, s1, s2, s3, q0, q1, q2, q3);
  DPP8("row_ror:8", s0, s1, s2, s3, q0, q1, q2, q3);
  f32x4 svv = {s0, s1, s2, s3}, qvv = {q0, q1, q2, q3};
  mu = svv * (1.f / 64.f);
  f32x4 var = qvv * (1.f / 64.f) - mu * mu;
  rs[0] = rsqrtf(var[0] + LN_EPS); rs[1] = rsqrtf(var[1] + LN_EPS);
  rs[2] = rsqrtf(var[2] + LN_EPS); rs[3] = rsqrtf(var[3] + LN_EPS);
}

// LDS strides (shorts): must be multiples of 8 shorts (16B) for b128 rows.
#define SW1 168
#define SW2 72

__global__ __launch_bounds__(TPB, 3)
void edge_mlp_mfma(const float* __restrict__ nf, const int* __restrict__ ei,
                   const float* __restrict__ ea,
                   const float* __restrict__ W1, const float* __restrict__ b1,
                   const float* __restrict__ g1, const float* __restrict__ be1,
                   const float* __restrict__ W2, const float* __restrict__ b2,
                   const float* __restrict__ g2, const float* __restrict__ be2,
                   const float* __restrict__ W3, const float* __restrict__ b3,
                   float* __restrict__ out, int E, int ntiles) {
  __shared__ short W1T[64 * SW1];      // [n][k], k 0..159 (144 real + 16 zero)
  __shared__ short W2T[64 * SW2];      // [n][k]
  __shared__ short HB[4][16 * SW2];    // per-wave h1 tile (16 edges x 64)

  const int tid  = threadIdx.x;
  const int lane = tid & 63;
  const int wv   = tid >> 6;
  const int ln   = lane & 15;
  const int quad = lane >> 4;

  // ---- Stage W1^T, W2^T as bf16 into LDS ----
  for (int i = tid; i < 9216; i += TPB) {
    int n = i & 63, k = i >> 6;
    W1T[n * SW1 + k] = bf16rne(W1[k * 64 + n]);
  }
  for (int i = tid; i < 1024; i += TPB) {            // zero-pad k in [144,160)
    int n = i & 63, k = 144 + (i >> 6);
    W1T[n * SW1 + k] = 0;
  }
  for (int i = tid; i < 4096; i += TPB) {
    int n = i & 63, k = i >> 6;
    W2T[n * SW2 + k] = bf16rne(W2[k * 64 + n]);
  }
  __syncthreads();   // the ONLY block barrier

  // ---- Per-lane n-indexed params (n = ln + 16*jt) ----
  float g1v[4], be1v[4], g2v[4], be2v[4], W3v[4];
  f32x4 B1F[4], B2F[4];                // bias broadcast frags (MFMA C-input)
  #pragma unroll
  for (int jt = 0; jt < 4; ++jt) {
    int n = ln + 16 * jt;
    B1F[jt] = (f32x4)(b1[n]);  g1v[jt] = g1[n];  be1v[jt] = be1[n];
    B2F[jt] = (f32x4)(b2[n]);  g2v[jt] = g2[n];  be2v[jt] = be2[n];
    W3v[jt] = W3[n];
  }
  const float b3s = b3[0];

  // int64-vs-int32 index sniff (validated rounds 3-13)
  const bool idx64 = (__ballot(ei[2 * lane + 1] == 0) == ~0ull);

  // ---- Indices: current tile (sI/dI) and next tile (sN/dN) ----
  int sI[4], dI[4], sN[4], dN[4];
  {
    const int eb0 = blockIdx.x * 256 + wv * 64;
    #pragma unroll
    for (int mt = 0; mt < 4; ++mt) {
      int el = eb0 + mt * 16 + ln;
      int ec = el < E ? el : E - 1;
      if (idx64) { sI[mt] = ei[2 * ec]; dI[mt] = ei[2 * (E + ec)]; }
      else       { sI[mt] = ei[ec];     dI[mt] = ei[E + ec]; }
      sN[mt] = sI[mt]; dN[mt] = dI[mt];   // safe defaults for the last tile
    }
  }

  // ---- Gather in-flight buffer (one mt's worth) ----
  f32x4 raw[10];
  auto issue = [&](int s, int d, int el) {
    int ec = el < E ? el : E - 1;
    const float* sp = nf + (size_t)s * 64 + quad * 8;
    const float* dp = nf + (size_t)d * 64 + quad * 8;
    const float* ap = ea + (size_t)ec * 16 + (quad & 1) * 8;
    raw[0] = *(const f32x4*)sp;        raw[1] = *(const f32x4*)(sp + 4);
    raw[2] = *(const f32x4*)(sp + 32); raw[3] = *(const f32x4*)(sp + 36);
    raw[4] = *(const f32x4*)dp;        raw[5] = *(const f32x4*)(dp + 4);
    raw[6] = *(const f32x4*)(dp + 32); raw[7] = *(const f32x4*)(dp + 36);
    raw[8] = *(const f32x4*)ap;        raw[9] = *(const f32x4*)(ap + 4);
  };

  // prologue: first mt's gather in flight
  issue(sI[0], dI[0], blockIdx.x * 256 + wv * 64 + ln);

  for (int tile = blockIdx.x; tile < ntiles; tile += gridDim.x) {
    const int ebase = tile * 256 + wv * 64;

    #pragma unroll
    for (int mt = 0; mt < 4; ++mt) {
      // ---- convert landed gather to bf16 A-fragments (frees raw[]) ----
      short8 afr[5];
      afr[0] = cvt8(raw[0], raw[1]);
      afr[1] = cvt8(raw[2], raw[3]);
      afr[2] = cvt8(raw[4], raw[5]);
      afr[3] = cvt8(raw[6], raw[7]);
      afr[4] = cvt8(raw[8], raw[9]);   // k>=144 lanes: B rows zero, value moot

      // ---- Layer 1: 20 MFMAs; bias enters as C of the t=0 MFMA ----
      f32x4 acc[4];                    // [jt]
      #pragma unroll
      for (int jt = 0; jt < 4; ++jt) {
        short8 bfr = *(const short8*)&W1T[(jt * 16 + ln) * SW1 + quad * 8];
        acc[jt] = __builtin_amdgcn_mfma_f32_16x16x32_bf16(
            afr[0], bfr, B1F[jt], 0, 0, 0);
      }
      #pragma unroll
      for (int t = 1; t < 5; ++t)
        #pragma unroll
        for (int jt = 0; jt < 4; ++jt) {
          short8 bfr = *(const short8*)&W1T[(jt * 16 + ln) * SW1 + t * 32 + quad * 8];
          acc[jt] = __builtin_amdgcn_mfma_f32_16x16x32_bf16(
              afr[t], bfr, acc[jt], 0, 0, 0);
        }

      // ---- Prefetch next tile's indices (consumed at mt==3) ----
      if (mt == 1) {
        int ntile = tile + gridDim.x;
        if (ntile < ntiles) {
          const int nb = ntile * 256 + wv * 64;
          #pragma unroll
          for (int m2 = 0; m2 < 4; ++m2) {
            int el = nb + m2 * 16 + ln;
            int ec = el < E ? el : E - 1;
            if (idx64) { sN[m2] = ei[2 * ec]; dN[m2] = ei[2 * (E + ec)]; }
            else       { sN[m2] = ei[ec];     dN[m2] = ei[E + ec]; }
          }
        }
      }

      // ---- Issue next mt's gather: latency hides under this epilogue ----
      if (mt < 3) issue(sI[mt + 1], dI[mt + 1], ebase + (mt + 1) * 16 + ln);
      else        issue(sN[0], dN[0], (tile + (int)gridDim.x) * 256 + wv * 64 + ln);

      // ---- Epilogue (wave-private; fused-DPP reductions, no barriers) ----
      f32x4 mu, rs;
      lnstats(acc[0], acc[1], acc[2], acc[3], mu, rs);

      #pragma unroll
      for (int jt = 0; jt < 4; ++jt)
        #pragma unroll
        for (int r = 0; r < 4; ++r) {
          float h = (acc[jt][r] - mu[r]) * rs[r] * g1v[jt] + be1v[jt];
          h = fmaxf(h, NEG_SLOPE * h);
          HB[wv][(quad * 4 + r) * SW2 + ln + 16 * jt] = (short)cvtpk(h, h);
        }
      // wave-private handoff: DS in-order per wave; drain writes then read
      asm volatile("s_waitcnt lgkmcnt(0)" ::: "memory");

      // ---- Layer 2: 8 MFMAs; bias as C of the t2=0 MFMA ----
      f32x4 acc2[4];
      {
        short8 a2 = *(const short8*)&HB[wv][ln * SW2 + quad * 8];
        #pragma unroll
        for (int jt = 0; jt < 4; ++jt) {
          short8 w2f = *(const short8*)&W2T[(jt * 16 + ln) * SW2 + quad * 8];
          acc2[jt] = __builtin_amdgcn_mfma_f32_16x16x32_bf16(
              a2, w2f, B2F[jt], 0, 0, 0);
        }
      }
      {
        short8 a2 = *(const short8*)&HB[wv][ln * SW2 + 32 + quad * 8];
        #pragma unroll
        for (int jt = 0; jt < 4; ++jt) {
          short8 w2f = *(const short8*)&W2T[(jt * 16 + ln) * SW2 + 32 + quad * 8];
          acc2[jt] = __builtin_amdgcn_mfma_f32_16x16x32_bf16(
              a2, w2f, acc2[jt], 0, 0, 0);
        }
      }

      f32x4 mu2, rs2;
      lnstats(acc2[0], acc2[1], acc2[2], acc2[3], mu2, rs2);

      float p0 = 0.f, p1 = 0.f, p2 = 0.f, p3 = 0.f;
      #pragma unroll
      for (int jt = 0; jt < 4; ++jt) {
        float h0 = (acc2[jt][0] - mu2[0]) * rs2[0] * g2v[jt] + be2v[jt];
        float h1 = (acc2[jt][1] - mu2[1]) * rs2[1] * g2v[jt] + be2v[jt];
        float h2 = (acc2[jt][2] - mu2[2]) * rs2[2] * g2v[jt] + be2v[jt];
        float h3 = (acc2[jt][3] - mu2[3]) * rs2[3] * g2v[jt] + be2v[jt];
        h0 = fmaxf(h0, NEG_SLOPE * h0); h1 = fmaxf(h1, NEG_SLOPE * h1);
        h2 = fmaxf(h2, NEG_SLOPE * h2); h3 = fmaxf(h3, NEG_SLOPE * h3);
        p0 = fmaf(h0, W3v[jt], p0); p1 = fmaf(h1, W3v[jt], p1);
        p2 = fmaf(h2, W3v[jt], p2); p3 = fmaf(h3, W3v[jt], p3);
      }
      DPP4("row_ror:1", p0, p1, p2, p3);
      DPP4("row_ror:2", p0, p1, p2, p3);
      DPP4("row_ror:4", p0, p1, p2, p3);
      DPP4("row_ror:8", p0, p1, p2, p3);

      if (ln < 4) {       // lanes 0-3 of each quad store edges quad*4 + ln
        int e = ebase + mt * 16 + quad * 4 + ln;
        if (e < E) {
          float v = (ln == 0) ? p0 : (ln == 1) ? p1 : (ln == 2) ? p2 : p3;
          out[e] = v + b3s;
        }
      }
    }

    // rotate next-tile indices into place
    #pragma unroll
    for (int m2 = 0; m2 < 4; ++m2) { sI[m2] = sN[m2]; dI[m2] = dN[m2]; }
  }
}

extern "C" void kernel_launch(void* const* d_in, const int* in_sizes, int n_in,
                              void* d_out, int out_size, void* d_ws, size_t ws_size,
                              hipStream_t stream) {
  const float* nf = (const float*)d_in[0];
  const int*   ei = (const int*)d_in[1];
  const float* ea = (const float*)d_in[2];

  const int E = out_size;
  const int ntiles = (E + 255) / 256;
  const int blocks = ntiles < 2048 ? ntiles : 2048;

  edge_mlp_mfma<<<blocks, TPB, 0, stream>>>(
      nf, ei, ea,
      (const float*)d_in[3],  (const float*)d_in[4],
      (const float*)d_in[5],  (const float*)d_in[6],
      (const float*)d_in[7],  (const float*)d_in[8],
      (const float*)d_in[9],  (const float*)d_in[10],
      (const float*)d_in[11], (const float*)d_in[12],
      (float*)d_out, E, ntiles);
}